// Round 7
// baseline (11831.256 us; speedup 1.0000x reference)
//
#include <hip/hip_runtime.h>
#include <math.h>

#define TT 2048
#define NB 64
#define EE 256
#define HH 256
#define PJ 16    // j-partitions recorded in part[] (unchanged layout)
#define XLD 288  // swizzled row: 256 + 4 pad per 32 floats
#define RS1 280  // red_s kc stride
#define RS2 72   // red_s batch stride

typedef float f32x4 __attribute__((ext_vector_type(4)));

__device__ __forceinline__ float sigf(float x) { return 1.f / (1.f + expf(-x)); }

__device__ __forceinline__ unsigned long long packh(unsigned tag, float v) {
    union { float f; unsigned u; } c; c.f = v;
    return ((unsigned long long)tag << 32) | (unsigned long long)c.u;
}

// R12: R9's structure (512 thr, 2 waves/SIMD, tagged-spin h exchange,
// wave0 register epilogue, 2 barriers/step) with the x path moved OFF LDS:
// each thread loads its own (2 batches x 32k) x-chunk straight from emb
// into registers (16 float4, plain loads -- nt hurt in R11). Loads are
// issued right after B1 and consumed next iteration; the vmcnt drain at B2
// sits ~1000cy later, fully covering L2/L3 latency. This removes half the
// per-step ds_read_b128 instructions (the CU-wide LDS-issue floor) plus
// all x staging. 80KB dynamic LDS pad forces 1 WG/CU (R9's outlier fix).
// All per-value fp op orders identical to R9 (bitwise outputs, absmax 0).
__global__ __launch_bounds__(512, 2)
void lstm_kernel(const int* __restrict__ sent, const float* __restrict__ emb,
                 const float* __restrict__ W_ih, const float* __restrict__ W_hh,
                 const float* __restrict__ b_ih, const float* __restrict__ b_hh,
                 const float* __restrict__ W_z,
                 unsigned long long* __restrict__ hbuf,
                 float* __restrict__ part)
{
    __shared__ float h_sw[4 * XLD];
    __shared__ float red_s[8 * RS1];
    __shared__ float p_s[64];
    extern __shared__ float dyn_pad[];   // occupancy pad (launch config)

    const int tid  = threadIdx.x;
    if (tid == 0 && sent[0] < 0) ((volatile float*)dyn_pad)[0] = 0.f;

    // XCD-clustering swizzle (heuristic)
    const int xcd  = blockIdx.x & 7;
    const int slot = blockIdx.x >> 3;       // 0..31
    const int grp  = xcd * 2 + (slot >> 4); // 0..15 batch group
    const int jgrp = slot & 15;             // 0..15 j-slice
    const int b0   = grp << 2;
    const int j0   = jgrp << 4;

    const int wv    = tid >> 6;             // 0..7
    const int lane  = tid & 63;
    const int bp    = wv & 1;               // batch pair (0: b0,b1  1: b2,b3)
    const int kc    = (wv >> 1) * 2 + (lane & 1);  // 0..7 k-chunk (32 floats)
    const int rg    = lane >> 1;            // 0..31 row-group (2 rows)
    const int kbase = kc << 5;

    // ---- W chunks -> VGPRs: 2 rows x 8 float4 per matrix = 128 VGPRs ----
    float4 wih_r[16], whh_r[16];
    #pragma unroll
    for (int i = 0; i < 2; ++i) {
        int lr = rg * 2 + i;                          // row 0..63
        long grow = (long)((lr >> 4) * HH + j0 + (lr & 15));
        const float4* wi = (const float4*)(W_ih + grow * EE + kbase);
        const float4* wh = (const float4*)(W_hh + grow * EE + kbase);
        #pragma unroll
        for (int mi = 0; mi < 8; ++mi) {
            wih_r[i * 8 + mi] = wi[mi];
            whh_r[i * 8 + mi] = wh[mi];
        }
    }

    // ---- wave0 epilogue state (one (b,jj) output per lane) ----
    const int eb  = lane >> 4;   // batch 0..3
    const int ejj = lane & 15;   // j within slice
    float bias_g[4]; float wz_r = 0.f; float c_reg = 0.f;
    if (wv == 0) {
        #pragma unroll
        for (int g = 0; g < 4; ++g)
            bias_g[g] = b_ih[g * HH + j0 + ejj] + b_hh[g * HH + j0 + ejj];
        wz_r = W_z[j0 + ejj];
    }

    // consumer mapping: 2 tagged ull per thread (4 batches x 256 j covered)
    const int cb    = tid >> 7;              // 0..3
    const int cj    = (tid & 127) << 1;      // 0..254 even
    const int cphys = cj + ((cj >> 5) << 2);

    // ---- x chunks in registers: xv[jb*8+mi] = emb[tok(b)][kbase+mi*4..] --
    const int bA = b0 + 2 * bp;              // this thread's two batches
    const int bB = bA + 1;
    f32x4 xv[16];
    {   // prologue: x(0)
        int t0 = sent[0 * NB + bA];
        int t1 = sent[0 * NB + bB];
        const f32x4* e0 = (const f32x4*)(emb + (long)t0 * EE + kbase);
        const f32x4* e1 = (const f32x4*)(emb + (long)t1 * EE + kbase);
        #pragma unroll
        for (int mi = 0; mi < 8; ++mi) { xv[mi] = e0[mi]; xv[8 + mi] = e1[mi]; }
    }

    for (int t = 0; t < TT; ++t) {
        const bool pf = (t + 1 < TT);

        // ---- phase 1: x partials from registers ----
        float4 acc[2][2];   // [row i][batch jb]
        #pragma unroll
        for (int i = 0; i < 2; ++i)
            #pragma unroll
            for (int j = 0; j < 2; ++j)
                acc[i][j] = make_float4(0.f, 0.f, 0.f, 0.f);

        #pragma unroll
        for (int jb = 0; jb < 2; ++jb) {
            #pragma unroll
            for (int mi = 0; mi < 8; ++mi) {
                f32x4 x4 = xv[jb * 8 + mi];
                #pragma unroll
                for (int i = 0; i < 2; ++i) {
                    float4 w = wih_r[i * 8 + mi];
                    acc[i][jb].x += w.x * x4.x; acc[i][jb].y += w.y * x4.y;
                    acc[i][jb].z += w.z * x4.z; acc[i][jb].w += w.w * x4.w;
                }
            }
        }

        // ---- spin-consume h_{t-1} (R9's tagged protocol, unchanged) ----
        if (t > 0) {
            const unsigned want = (unsigned)t;   // h_{t-1} carries tag t
            unsigned long long* hp =
                hbuf + ((size_t)(((t - 1) & 1) * NB + b0 + cb)) * HH + cj;
            unsigned long long v0, v1;
            v0 = __hip_atomic_load(hp + 0, __ATOMIC_RELAXED, __HIP_MEMORY_SCOPE_AGENT);
            v1 = __hip_atomic_load(hp + 1, __ATOMIC_RELAXED, __HIP_MEMORY_SCOPE_AGENT);
            while ((unsigned)(v0 >> 32) != want)
                v0 = __hip_atomic_load(hp + 0, __ATOMIC_RELAXED, __HIP_MEMORY_SCOPE_AGENT);
            while ((unsigned)(v1 >> 32) != want)
                v1 = __hip_atomic_load(hp + 1, __ATOMIC_RELAXED, __HIP_MEMORY_SCOPE_AGENT);
            union { unsigned u; float f; } c0, c1;
            c0.u = (unsigned)v0; c1.u = (unsigned)v1;
            *(float2*)(&h_sw[cb * XLD + cphys]) = make_float2(c0.f, c1.f);
        }
        __syncthreads();   // B1: h_sw ready

        // part-sum for step t-1: wave1 lanes 0..3, off the critical path
        if (t > 0 && wv == 1 && lane < 4) {
            float s = 0.f;
            #pragma unroll
            for (int jj = 0; jj < 16; ++jj) s += p_s[lane * 16 + jj];
            part[((size_t)(t - 1) * PJ + jgrp) * NB + b0 + lane] = s;
        }

        // ---- issue x(t+1) loads now; drained at B2 (~1000cy of cover) ----
        if (pf) {
            int t0 = sent[(t + 1) * NB + bA];
            int t1 = sent[(t + 1) * NB + bB];
            const f32x4* e0 = (const f32x4*)(emb + (long)t0 * EE + kbase);
            const f32x4* e1 = (const f32x4*)(emb + (long)t1 * EE + kbase);
            #pragma unroll
            for (int mi = 0; mi < 8; ++mi) { xv[mi] = e0[mi]; xv[8 + mi] = e1[mi]; }
        }

        // ---- phase 2: h partials into same accumulators ----
        if (t > 0) {
            #pragma unroll
            for (int jb = 0; jb < 2; ++jb) {
                const float* hb = &h_sw[(2 * bp + jb) * XLD + kc * 36];
                #pragma unroll
                for (int mi = 0; mi < 8; ++mi) {
                    float4 hv4 = *(const float4*)(hb + mi * 4);
                    #pragma unroll
                    for (int i = 0; i < 2; ++i) {
                        float4 w = whh_r[i * 8 + mi];
                        acc[i][jb].x += w.x * hv4.x; acc[i][jb].y += w.y * hv4.y;
                        acc[i][jb].z += w.z * hv4.z; acc[i][jb].w += w.w * hv4.w;
                    }
                }
            }
        }
        // horizontal-add partials, write to reduction scratch (float2 per b)
        #pragma unroll
        for (int jb = 0; jb < 2; ++jb) {
            int b = 2 * bp + jb;
            float2 v;
            v.x = (acc[0][jb].x + acc[0][jb].y) + (acc[0][jb].z + acc[0][jb].w);
            v.y = (acc[1][jb].x + acc[1][jb].y) + (acc[1][jb].z + acc[1][jb].w);
            *(float2*)(&red_s[kc * RS1 + b * RS2 + rg * 2]) = v;
        }
        __syncthreads();   // B2: red_s ready; x(t+1) loads completed here

        // ---- epilogue: wave0 (reduce + gates + tagged publish + p_s) ----
        // Waves 1-7 fall through to phase1(t+1); their red_s writes for t+1
        // happen after B1(t+1), which wave0 reaches only after its reads.
        if (wv == 0) {
            float sg[4];
            #pragma unroll
            for (int g = 0; g < 4; ++g) {
                float s = bias_g[g];
                #pragma unroll
                for (int k2 = 0; k2 < 8; ++k2)
                    s += red_s[k2 * RS1 + eb * RS2 + g * 16 + ejj];
                sg[g] = s;
            }
            float cn = sigf(sg[1]) * c_reg + sigf(sg[0]) * tanhf(sg[2]);
            float hn = sigf(sg[3]) * tanhf(cn);
            c_reg = cn;
            p_s[lane] = hn * wz_r;
            __hip_atomic_store(
                hbuf + ((size_t)((t & 1) * NB + b0 + eb)) * HH + j0 + ejj,
                packh((unsigned)(t + 1), hn),
                __ATOMIC_RELAXED, __HIP_MEMORY_SCOPE_AGENT);
        }
    }

    // final part-sum (t = TT-1)
    __syncthreads();
    if (wv == 1 && lane < 4) {
        float s = 0.f;
        #pragma unroll
        for (int jj = 0; jj < 16; ++jj) s += p_s[lane * 16 + jj];
        part[((size_t)(TT - 1) * PJ + jgrp) * NB + b0 + lane] = s;
    }
}

__global__ void pz_kernel(const float* __restrict__ part,
                          const float* __restrict__ noise,
                          const float* __restrict__ b_z,
                          float* __restrict__ out)
{
    int idx = blockIdx.x * blockDim.x + threadIdx.x;  // t*64 + b
    if (idx >= TT * NB) return;
    int t = idx >> 6, b = idx & 63;
    float s = b_z[0];
    #pragma unroll
    for (int jg = 0; jg < PJ; ++jg) s += part[(t * PJ + jg) * NB + b];
    float pz = 1.f / (1.f + expf(-s));
    out[idx] = pz;
    out[TT * NB + idx] = (noise[idx] < pz) ? 1.f : 0.f;
}

// One block per batch column: stable compaction of tokens where z==1.
__global__ void compact_kernel(const int* __restrict__ sent,
                               const float* __restrict__ zbuf,
                               float* __restrict__ rat,
                               float* __restrict__ zsz)
{
    __shared__ float rat_s[TT];
    __shared__ int scan_s[256];
    int b = blockIdx.x, tid = threadIdx.x;
    int zloc[8];
    int base = tid * 8;
    int c = 0;
    #pragma unroll
    for (int i = 0; i < 8; ++i) {
        zloc[i] = (zbuf[(base + i) * NB + b] != 0.f) ? 1 : 0;
        c += zloc[i];
    }
    scan_s[tid] = c;
    for (int i = tid; i < TT; i += 256) rat_s[i] = 0.f;
    __syncthreads();
    for (int off = 1; off < 256; off <<= 1) {
        int v = scan_s[tid];
        int add = (tid >= off) ? scan_s[tid - off] : 0;
        __syncthreads();
        scan_s[tid] = v + add;
        __syncthreads();
    }
    int total = scan_s[255];
    int pos = scan_s[tid] - c;  // exclusive prefix
    #pragma unroll
    for (int i = 0; i < 8; ++i) {
        if (zloc[i]) { rat_s[pos] = (float)sent[(base + i) * NB + b]; ++pos; }
    }
    __syncthreads();
    for (int i = tid; i < TT; i += 256) rat[i * NB + b] = rat_s[i];
    if (tid == 0) zsz[b] = (float)total;
}

extern "C" void kernel_launch(void* const* d_in, const int* in_sizes, int n_in,
                              void* d_out, int out_size, void* d_ws, size_t ws_size,
                              hipStream_t stream)
{
    const int*   sent  = (const int*)d_in[0];
    const float* noise = (const float*)d_in[1];
    const float* emb   = (const float*)d_in[2];
    const float* W_ih  = (const float*)d_in[3];
    const float* W_hh  = (const float*)d_in[4];
    const float* b_ih  = (const float*)d_in[5];
    const float* b_hh  = (const float*)d_in[6];
    const float* W_z   = (const float*)d_in[7];
    const float* b_z   = (const float*)d_in[8];
    float* out = (float*)d_out;

    char* ws = (char*)d_ws;
    unsigned long long* hbuf = (unsigned long long*)ws;     // 2*64*256*8 = 256 KB
    float* part = (float*)(ws + 262144);                    // 2048*16*64*4 = 8 MB

    // tags must start != any expected tag (1..2048)
    (void)hipMemsetAsync(hbuf, 0, 2 * NB * HH * sizeof(unsigned long long), stream);

    // ~14KB static + 80KB dynamic LDS -> ~94KB -> exactly 1 WG/CU
    lstm_kernel<<<256, 512, 81920, stream>>>(sent, emb, W_ih, W_hh, b_ih, b_hh,
                                             W_z, hbuf, part);
    pz_kernel<<<(TT * NB) / 256, 256, 0, stream>>>(part, noise, b_z, out);
    compact_kernel<<<NB, 256, 0, stream>>>(sent, out + TT * NB,
                                           out + 2 * TT * NB, out + 3 * TT * NB);
}

// Round 8
// 6199.417 us; speedup vs baseline: 1.9084x; 1.9084x over previous
//
#include <hip/hip_runtime.h>
#include <math.h>

#define TT 2048
#define NB 64
#define EE 256
#define HH 256
#define PJ 16    // j-partitions recorded in part[] (unchanged layout)
#define XLD 288  // swizzled row: 256 + 4 pad per 32 floats
#define RS1 280  // red_s kc stride
#define RS2 72   // red_s batch stride

typedef float f32x4 __attribute__((ext_vector_type(4)));

__device__ __forceinline__ float sigf(float x) { return 1.f / (1.f + expf(-x)); }

__device__ __forceinline__ unsigned long long packh(unsigned tag, float v) {
    union { float f; unsigned u; } c; c.f = v;
    return ((unsigned long long)tag << 32) | (unsigned long long)c.u;
}

// R13: R9 (best, 5627us) + wave role split for emb-latency hiding.
//  - Waves 4-7 = staging: issue their single 16B emb load at LOOP TOP
//    (cover = phase1 + spin window + phase2 ~2000cy, hides HBM), ds_write
//    x_sw pre-B2, and NEVER poll -- so nothing drains their load early.
//  - Waves 0-3 = consumers: R6's mapping, 4 tagged words/thread, spin
//    placed after phase1 (R9's proven protocol, unchanged).
//  - Tokens prefetched one step ahead in registers (wave-uniform s_load).
//  - Weights stay r=2 (128 VGPR); added per-thread state = 1 f32x4 + token
//    (R12's remat disaster avoided).
//  - 64KB dynamic LDS pad -> 1 WG/CU.
// All per-value fp op orders and transported bits identical to R9
// (bitwise outputs, absmax 0).
__global__ __launch_bounds__(512, 2)
void lstm_kernel(const int* __restrict__ sent, const float* __restrict__ emb,
                 const float* __restrict__ W_ih, const float* __restrict__ W_hh,
                 const float* __restrict__ b_ih, const float* __restrict__ b_hh,
                 const float* __restrict__ W_z,
                 unsigned long long* __restrict__ hbuf,
                 float* __restrict__ part)
{
    __shared__ float x_sw[4 * XLD];
    __shared__ float h_sw[4 * XLD];
    __shared__ float red_s[8 * RS1];
    __shared__ float p_s[64];
    extern __shared__ float dyn_pad[];   // occupancy pad (launch config)

    const int tid  = threadIdx.x;
    if (tid == 0 && sent[0] < 0) ((volatile float*)dyn_pad)[0] = 0.f;

    // XCD-clustering swizzle (heuristic)
    const int xcd  = blockIdx.x & 7;
    const int slot = blockIdx.x >> 3;       // 0..31
    const int grp  = xcd * 2 + (slot >> 4); // 0..15 batch group
    const int jgrp = slot & 15;             // 0..15 j-slice
    const int b0   = grp << 2;
    const int j0   = jgrp << 4;

    const int wv    = tid >> 6;             // 0..7
    const int lane  = tid & 63;
    const int bp    = wv & 1;               // batch pair (0: b0,b1  1: b2,b3)
    const int kc    = (wv >> 1) * 2 + (lane & 1);  // 0..7 k-chunk (32 floats)
    const int rg    = lane >> 1;            // 0..31 row-group (2 rows)
    const int kbase = kc << 5;

    // ---- W chunks -> VGPRs: 2 rows x 8 float4 per matrix = 128 VGPRs ----
    float4 wih_r[16], whh_r[16];
    #pragma unroll
    for (int i = 0; i < 2; ++i) {
        int lr = rg * 2 + i;                          // row 0..63
        long grow = (long)((lr >> 4) * HH + j0 + (lr & 15));
        const float4* wi = (const float4*)(W_ih + grow * EE + kbase);
        const float4* wh = (const float4*)(W_hh + grow * EE + kbase);
        #pragma unroll
        for (int mi = 0; mi < 8; ++mi) {
            wih_r[i * 8 + mi] = wi[mi];
            whh_r[i * 8 + mi] = wh[mi];
        }
    }

    // ---- wave0 epilogue state (one (b,jj) output per lane) ----
    const int eb  = lane >> 4;   // batch 0..3
    const int ejj = lane & 15;   // j within slice
    float bias_g[4]; float wz_r = 0.f; float c_reg = 0.f;
    if (wv == 0) {
        #pragma unroll
        for (int g = 0; g < 4; ++g)
            bias_g[g] = b_ih[g * HH + j0 + ejj] + b_hh[g * HH + j0 + ejj];
        wz_r = W_z[j0 + ejj];
    }

    // consumer mapping (waves 0-3): 4 tagged words/thread (R6's mapping)
    const int cb    = tid >> 6;              // 0..3 (valid tid<256)
    const int cj    = (tid & 63) << 2;       // 0..252
    const int cphys = cj + ((cj >> 5) << 2);

    // staging mapping (waves 4-7): one batch row per wave, 16B per thread
    const int st   = tid - 256;
    const int stb  = st >> 6;                // 0..3 (valid st>=0)
    const int ste4 = st & 63;

    int tok_cur = 0;   // token for the x-row this staging thread loads next
    if (st >= 0) {     // prologue: stage x(0); prepare token for t=1
        int tk0 = sent[0 * NB + b0 + stb];
        f32x4 xv0 = ((const f32x4*)(emb + (long)tk0 * EE))[ste4];
        int phys = 4 * ste4 + ((ste4 >> 3) << 2);
        *(f32x4*)(&x_sw[stb * XLD + phys]) = xv0;
        tok_cur = sent[1 * NB + b0 + stb];
    }
    __syncthreads();

    for (int t = 0; t < TT; ++t) {
        const bool pf = (t + 1 < TT);

        // ---- staging waves: issue x(t+1) load NOW (~2000cy of cover) ----
        f32x4 xv;
        if (st >= 0 && pf) {
            xv = ((const f32x4*)(emb + (long)tok_cur * EE))[ste4];
            if (t + 2 < TT) tok_cur = sent[(t + 2) * NB + b0 + stb];
        }

        // ---- phase 1: x partials (x_sw staged previous iteration) ----
        float4 acc[2][2];   // [row i][batch jb]
        #pragma unroll
        for (int i = 0; i < 2; ++i)
            #pragma unroll
            for (int j = 0; j < 2; ++j)
                acc[i][j] = make_float4(0.f, 0.f, 0.f, 0.f);

        #pragma unroll
        for (int jb = 0; jb < 2; ++jb) {
            const float* xb = &x_sw[(2 * bp + jb) * XLD + kc * 36];
            #pragma unroll
            for (int mi = 0; mi < 8; ++mi) {
                float4 xv4 = *(const float4*)(xb + mi * 4);
                #pragma unroll
                for (int i = 0; i < 2; ++i) {
                    float4 w = wih_r[i * 8 + mi];
                    acc[i][jb].x += w.x * xv4.x; acc[i][jb].y += w.y * xv4.y;
                    acc[i][jb].z += w.z * xv4.z; acc[i][jb].w += w.w * xv4.w;
                }
            }
        }

        // ---- consumers (waves 0-3): spin 4 tagged words, fill h_sw ----
        if (t > 0 && tid < 256) {
            const unsigned want = (unsigned)t;   // h_{t-1} carries tag t
            unsigned long long* hp =
                hbuf + ((size_t)(((t - 1) & 1) * NB + b0 + cb)) * HH + cj;
            unsigned long long v0, v1, v2, v3;
            v0 = __hip_atomic_load(hp + 0, __ATOMIC_RELAXED, __HIP_MEMORY_SCOPE_AGENT);
            v1 = __hip_atomic_load(hp + 1, __ATOMIC_RELAXED, __HIP_MEMORY_SCOPE_AGENT);
            v2 = __hip_atomic_load(hp + 2, __ATOMIC_RELAXED, __HIP_MEMORY_SCOPE_AGENT);
            v3 = __hip_atomic_load(hp + 3, __ATOMIC_RELAXED, __HIP_MEMORY_SCOPE_AGENT);
            while ((unsigned)(v0 >> 32) != want)
                v0 = __hip_atomic_load(hp + 0, __ATOMIC_RELAXED, __HIP_MEMORY_SCOPE_AGENT);
            while ((unsigned)(v1 >> 32) != want)
                v1 = __hip_atomic_load(hp + 1, __ATOMIC_RELAXED, __HIP_MEMORY_SCOPE_AGENT);
            while ((unsigned)(v2 >> 32) != want)
                v2 = __hip_atomic_load(hp + 2, __ATOMIC_RELAXED, __HIP_MEMORY_SCOPE_AGENT);
            while ((unsigned)(v3 >> 32) != want)
                v3 = __hip_atomic_load(hp + 3, __ATOMIC_RELAXED, __HIP_MEMORY_SCOPE_AGENT);
            union { unsigned u; float f; } c0, c1, c2, c3;
            c0.u = (unsigned)v0; c1.u = (unsigned)v1;
            c2.u = (unsigned)v2; c3.u = (unsigned)v3;
            *(float4*)(&h_sw[cb * XLD + cphys]) =
                make_float4(c0.f, c1.f, c2.f, c3.f);
        }
        __syncthreads();   // B1: h_sw ready; x_sw(t) reads done

        // part-sum for step t-1: wave1 lanes 0..3, off the critical path
        if (t > 0 && wv == 1 && lane < 4) {
            float s = 0.f;
            #pragma unroll
            for (int jj = 0; jj < 16; ++jj) s += p_s[lane * 16 + jj];
            part[((size_t)(t - 1) * PJ + jgrp) * NB + b0 + lane] = s;
        }

        // ---- phase 2: h partials into same accumulators ----
        if (t > 0) {
            #pragma unroll
            for (int jb = 0; jb < 2; ++jb) {
                const float* hb = &h_sw[(2 * bp + jb) * XLD + kc * 36];
                #pragma unroll
                for (int mi = 0; mi < 8; ++mi) {
                    float4 hv4 = *(const float4*)(hb + mi * 4);
                    #pragma unroll
                    for (int i = 0; i < 2; ++i) {
                        float4 w = whh_r[i * 8 + mi];
                        acc[i][jb].x += w.x * hv4.x; acc[i][jb].y += w.y * hv4.y;
                        acc[i][jb].z += w.z * hv4.z; acc[i][jb].w += w.w * hv4.w;
                    }
                }
            }
        }
        // horizontal-add partials, write to reduction scratch (float2 per b)
        #pragma unroll
        for (int jb = 0; jb < 2; ++jb) {
            int b = 2 * bp + jb;
            float2 v;
            v.x = (acc[0][jb].x + acc[0][jb].y) + (acc[0][jb].z + acc[0][jb].w);
            v.y = (acc[1][jb].x + acc[1][jb].y) + (acc[1][jb].z + acc[1][jb].w);
            *(float2*)(&red_s[kc * RS1 + b * RS2 + rg * 2]) = v;
        }
        if (st >= 0 && pf) {   // stage next x (readers finished pre-B1)
            int phys = 4 * ste4 + ((ste4 >> 3) << 2);
            *(f32x4*)(&x_sw[stb * XLD + phys]) = xv;
        }
        __syncthreads();   // B2: red_s ready; x_sw staged for t+1

        // ---- epilogue: wave0 (reduce + gates + tagged publish + p_s) ----
        // Waves 1-7 fall through to phase1(t+1); their red_s/x_sw writes for
        // t+1 happen after B1(t+1), which wave0 reaches only after its reads.
        if (wv == 0) {
            float sg[4];
            #pragma unroll
            for (int g = 0; g < 4; ++g) {
                float s = bias_g[g];
                #pragma unroll
                for (int k2 = 0; k2 < 8; ++k2)
                    s += red_s[k2 * RS1 + eb * RS2 + g * 16 + ejj];
                sg[g] = s;
            }
            float cn = sigf(sg[1]) * c_reg + sigf(sg[0]) * tanhf(sg[2]);
            float hn = sigf(sg[3]) * tanhf(cn);
            c_reg = cn;
            p_s[lane] = hn * wz_r;
            __hip_atomic_store(
                hbuf + ((size_t)((t & 1) * NB + b0 + eb)) * HH + j0 + ejj,
                packh((unsigned)(t + 1), hn),
                __ATOMIC_RELAXED, __HIP_MEMORY_SCOPE_AGENT);
        }
    }

    // final part-sum (t = TT-1)
    __syncthreads();
    if (wv == 1 && lane < 4) {
        float s = 0.f;
        #pragma unroll
        for (int jj = 0; jj < 16; ++jj) s += p_s[lane * 16 + jj];
        part[((size_t)(TT - 1) * PJ + jgrp) * NB + b0 + lane] = s;
    }
}

__global__ void pz_kernel(const float* __restrict__ part,
                          const float* __restrict__ noise,
                          const float* __restrict__ b_z,
                          float* __restrict__ out)
{
    int idx = blockIdx.x * blockDim.x + threadIdx.x;  // t*64 + b
    if (idx >= TT * NB) return;
    int t = idx >> 6, b = idx & 63;
    float s = b_z[0];
    #pragma unroll
    for (int jg = 0; jg < PJ; ++jg) s += part[(t * PJ + jg) * NB + b];
    float pz = 1.f / (1.f + expf(-s));
    out[idx] = pz;
    out[TT * NB + idx] = (noise[idx] < pz) ? 1.f : 0.f;
}

// One block per batch column: stable compaction of tokens where z==1.
__global__ void compact_kernel(const int* __restrict__ sent,
                               const float* __restrict__ zbuf,
                               float* __restrict__ rat,
                               float* __restrict__ zsz)
{
    __shared__ float rat_s[TT];
    __shared__ int scan_s[256];
    int b = blockIdx.x, tid = threadIdx.x;
    int zloc[8];
    int base = tid * 8;
    int c = 0;
    #pragma unroll
    for (int i = 0; i < 8; ++i) {
        zloc[i] = (zbuf[(base + i) * NB + b] != 0.f) ? 1 : 0;
        c += zloc[i];
    }
    scan_s[tid] = c;
    for (int i = tid; i < TT; i += 256) rat_s[i] = 0.f;
    __syncthreads();
    for (int off = 1; off < 256; off <<= 1) {
        int v = scan_s[tid];
        int add = (tid >= off) ? scan_s[tid - off] : 0;
        __syncthreads();
        scan_s[tid] = v + add;
        __syncthreads();
    }
    int total = scan_s[255];
    int pos = scan_s[tid] - c;  // exclusive prefix
    #pragma unroll
    for (int i = 0; i < 8; ++i) {
        if (zloc[i]) { rat_s[pos] = (float)sent[(base + i) * NB + b]; ++pos; }
    }
    __syncthreads();
    for (int i = tid; i < TT; i += 256) rat[i * NB + b] = rat_s[i];
    if (tid == 0) zsz[b] = (float)total;
}

extern "C" void kernel_launch(void* const* d_in, const int* in_sizes, int n_in,
                              void* d_out, int out_size, void* d_ws, size_t ws_size,
                              hipStream_t stream)
{
    const int*   sent  = (const int*)d_in[0];
    const float* noise = (const float*)d_in[1];
    const float* emb   = (const float*)d_in[2];
    const float* W_ih  = (const float*)d_in[3];
    const float* W_hh  = (const float*)d_in[4];
    const float* b_ih  = (const float*)d_in[5];
    const float* b_hh  = (const float*)d_in[6];
    const float* W_z   = (const float*)d_in[7];
    const float* b_z   = (const float*)d_in[8];
    float* out = (float*)d_out;

    char* ws = (char*)d_ws;
    unsigned long long* hbuf = (unsigned long long*)ws;     // 2*64*256*8 = 256 KB
    float* part = (float*)(ws + 262144);                    // 2048*16*64*4 = 8 MB

    // tags must start != any expected tag (1..2048)
    (void)hipMemsetAsync(hbuf, 0, 2 * NB * HH * sizeof(unsigned long long), stream);

    // ~18.5KB static + 64KB dynamic -> ~82.5KB -> exactly 1 WG/CU
    lstm_kernel<<<256, 512, 65536, stream>>>(sent, emb, W_ih, W_hh, b_ih, b_hh,
                                             W_z, hbuf, part);
    pz_kernel<<<(TT * NB) / 256, 256, 0, stream>>>(part, noise, b_z, out);
    compact_kernel<<<NB, 256, 0, stream>>>(sent, out + TT * NB,
                                           out + 2 * TT * NB, out + 3 * TT * NB);
}

// Round 9
// 4359.690 us; speedup vs baseline: 2.7138x; 1.4220x over previous
//
#include <hip/hip_runtime.h>
#include <math.h>

#define TT 2048
#define NB 64
#define EE 256
#define HH 256
#define PJ 16    // j-partitions recorded in part[] (unchanged layout)
#define XLD 288  // swizzled row: 256 + 4 pad per 32 floats
#define RS1 280  // red_s kc stride
#define RS2 72   // red_s batch stride
#define RBOFF (8 * RS1)   // context-B offset within red_s

typedef float f32x4 __attribute__((ext_vector_type(4)));

__device__ __forceinline__ float sigf(float x) { return 1.f / (1.f + expf(-x)); }

__device__ __forceinline__ unsigned long long packh(unsigned tag, float v) {
    union { float f; unsigned u; } c; c.f = v;
    return ((unsigned long long)tag << 32) | (unsigned long long)c.u;
}

// R14: dual-context stagger, rebuilt on R9's r=2 register budget.
// Each WG serves contexts A=(batches 2p,2p+1) and B=(32+2p,33+2p), same
// j-slice -> SAME 128 weight VGPRs (R7's 256-VGPR blowup avoided; x stays
// in LDS; accA/accB lifetimes disjoint). Per step: A-half {ph1, wide spin
// (4 waves x 2 words, R9 protocol), B1a, ph2+red, B2a, wv0 epilogue} then
// B-half mirrored (wv1 epilogue). Each context's publish->consume gap now
// spans the other context's whole half (~2000cy >> L2 latency) -> spins hit
// first poll; exchange latency leaves the critical path. Duty assignment
// keeps every wave's pending store/prefetch clear of its own polls:
// A-spin={2,3,4,7}, B-spin={4,5,6,7}, A-stage wv4(post-spin)/wv5(loop-top),
// B-stage wv6,7(post-B-spin); epilogue waves never poll what they publish.
// All fp op orders / transported bits identical to R9 (absmax 0).
__global__ __launch_bounds__(512, 2)
void lstm_kernel(const int* __restrict__ sent, const float* __restrict__ emb,
                 const float* __restrict__ W_ih, const float* __restrict__ W_hh,
                 const float* __restrict__ b_ih, const float* __restrict__ b_hh,
                 const float* __restrict__ W_z,
                 unsigned long long* __restrict__ hbuf,
                 float* __restrict__ part)
{
    __shared__ float x_sw[4 * XLD];     // rows 0-1: A, rows 2-3: B
    __shared__ float h_sw[4 * XLD];     // rows 0-1: A, rows 2-3: B
    __shared__ float red_s[2 * 8 * RS1];
    __shared__ float p_s[64];           // 0-31: A, 32-63: B
    extern __shared__ float dyn_pad[];  // occupancy pad

    const int tid  = threadIdx.x;
    if (tid == 0 && sent[0] < 0) ((volatile float*)dyn_pad)[0] = 0.f;

    // XCD-clustering swizzle (heuristic)
    const int xcd  = blockIdx.x & 7;
    const int slot = blockIdx.x >> 3;        // 0..31
    const int psys = xcd * 2 + (slot >> 4);  // 0..15 pair-system
    const int js   = slot & 15;              // j-slice
    const int bA0  = psys * 2;
    const int bB0  = 32 + psys * 2;
    const int j0   = js * 16;

    const int wv    = tid >> 6;              // 0..7
    const int lane  = tid & 63;
    const int bp    = wv & 1;                // batch within context
    const int kc    = (wv >> 1) * 2 + (lane & 1);  // 0..7 k-chunk
    const int rg    = lane >> 1;             // 0..31 row-group (2 rows)
    const int kbase = kc << 5;

    // ---- weights -> VGPRs (shared by both contexts): 128 VGPRs ----
    float4 wih_r[16], whh_r[16];
    #pragma unroll
    for (int i = 0; i < 2; ++i) {
        int lr = rg * 2 + i;
        long grow = (long)((lr >> 4) * HH + j0 + (lr & 15));
        const float4* wi = (const float4*)(W_ih + grow * EE + kbase);
        const float4* wh = (const float4*)(W_hh + grow * EE + kbase);
        #pragma unroll
        for (int mi = 0; mi < 8; ++mi) {
            wih_r[i * 8 + mi] = wi[mi];
            whh_r[i * 8 + mi] = wh[mi];
        }
    }

    // ---- epilogue state: wv0 -> A, wv1 -> B (lanes 0..31) ----
    const int eb  = (lane >> 4) & 1;  // batch 0..1 within context
    const int ejj = lane & 15;
    float bias_g[4]; float wz_r = 0.f; float c_reg = 0.f;
    if (wv < 2) {
        #pragma unroll
        for (int g = 0; g < 4; ++g)
            bias_g[g] = b_ih[g * HH + j0 + ejj] + b_hh[g * HH + j0 + ejj];
        wz_r = W_z[j0 + ejj];
    }

    // ---- spin mappings (R9 protocol: 2 tagged words per thread) ----
    // A-spin waves {2,3,4,7}; B-spin waves {4,5,6,7}
    const bool inA = (wv >= 2 && wv <= 4) || wv == 7;
    const bool inB = (wv >= 4);
    const int aidx = ((wv == 7 ? 3 : wv - 2) << 6) + lane;  // 0..255
    const int bidx = ((wv - 4) << 6) + lane;                // 0..255
    const int acb = aidx >> 7, acw = (aidx & 127) << 1;
    const int bcb = bidx >> 7, bcw = (bidx & 127) << 1;
    const int acph = acw + ((acw >> 5) << 2);
    const int bcph = bcw + ((bcw >> 5) << 2);

    // ---- staging: wv4,5 -> A rows, wv6,7 -> B rows (64 float4 each) ----
    const int stb   = wv & 1;                // wv4/6 -> batch0, wv5/7 -> batch1
    const int stRow = (wv >= 6 ? 2 : 0) + stb;
    const int sphys = 4 * lane + ((lane >> 3) << 2);
    int tok_st = 0;

    if (wv >= 4) {   // prologue: stage x(0) for both contexts
        int base = (wv >= 6) ? bB0 : bA0;
        int tk0 = sent[0 * NB + base + stb];
        f32x4 xv0 = ((const f32x4*)(emb + (long)tk0 * EE))[lane];
        *(f32x4*)(&x_sw[stRow * XLD + sphys]) = xv0;
        tok_st = sent[1 * NB + base + stb];
    }
    __syncthreads();

    for (int t = 0; t < TT; ++t) {
        const bool pf = (t + 1 < TT);
        const size_t parIn  = (size_t)(((t - 1) & 1) * NB);
        const size_t parOut = (size_t)((t & 1) * NB);

        f32x4 xst;   // staged x(t+1) in flight (waves 4-7)
        if (pf && wv == 5) {   // wv5 never A-polls: issue at loop top
            xst = ((const f32x4*)(emb + (long)tok_st * EE))[lane];
            if (t + 2 < TT) tok_st = sent[(t + 2) * NB + bA0 + stb];
        }

        // ================= A half =================
        float4 acc[2];
        acc[0] = make_float4(0.f, 0.f, 0.f, 0.f);
        acc[1] = make_float4(0.f, 0.f, 0.f, 0.f);
        {   // phase 1: x partials
            const float* xb = &x_sw[bp * XLD + kc * 36];
            #pragma unroll
            for (int mi = 0; mi < 8; ++mi) {
                float4 xv4 = *(const float4*)(xb + mi * 4);
                #pragma unroll
                for (int i = 0; i < 2; ++i) {
                    float4 w = wih_r[i * 8 + mi];
                    acc[i].x += w.x * xv4.x; acc[i].y += w.y * xv4.y;
                    acc[i].z += w.z * xv4.z; acc[i].w += w.w * xv4.w;
                }
            }
        }
        if (t > 0 && inA) {   // spin-consume h_A(t-1): 2 tagged words
            const unsigned want = (unsigned)t;
            unsigned long long* hp =
                hbuf + (parIn + bA0 + acb) * HH + acw;
            unsigned long long v0, v1;
            v0 = __hip_atomic_load(hp + 0, __ATOMIC_RELAXED, __HIP_MEMORY_SCOPE_AGENT);
            v1 = __hip_atomic_load(hp + 1, __ATOMIC_RELAXED, __HIP_MEMORY_SCOPE_AGENT);
            while ((unsigned)(v0 >> 32) != want)
                v0 = __hip_atomic_load(hp + 0, __ATOMIC_RELAXED, __HIP_MEMORY_SCOPE_AGENT);
            while ((unsigned)(v1 >> 32) != want)
                v1 = __hip_atomic_load(hp + 1, __ATOMIC_RELAXED, __HIP_MEMORY_SCOPE_AGENT);
            union { unsigned u; float f; } c0, c1;
            c0.u = (unsigned)v0; c1.u = (unsigned)v1;
            *(float2*)(&h_sw[acb * XLD + acph]) = make_float2(c0.f, c1.f);
        }
        if (pf && wv == 4) {   // A-stage issue after its polls
            xst = ((const f32x4*)(emb + (long)tok_st * EE))[lane];
            if (t + 2 < TT) tok_st = sent[(t + 2) * NB + bA0 + stb];
        }
        __syncthreads();   // B1a: h_A ready; x_A(t) reads done

        if (t > 0 && wv == 2 && lane < 2) {   // part A(t-1)
            float s = 0.f;
            #pragma unroll
            for (int jj = 0; jj < 16; ++jj) s += p_s[lane * 16 + jj];
            part[((size_t)(t - 1) * PJ + js) * NB + bA0 + lane] = s;
        }
        if (t > 0) {   // phase 2: h partials
            const float* hb = &h_sw[bp * XLD + kc * 36];
            #pragma unroll
            for (int mi = 0; mi < 8; ++mi) {
                float4 hv4 = *(const float4*)(hb + mi * 4);
                #pragma unroll
                for (int i = 0; i < 2; ++i) {
                    float4 w = whh_r[i * 8 + mi];
                    acc[i].x += w.x * hv4.x; acc[i].y += w.y * hv4.y;
                    acc[i].z += w.z * hv4.z; acc[i].w += w.w * hv4.w;
                }
            }
        }
        {   // horizontal add -> red_s (A region)
            float2 v;
            v.x = (acc[0].x + acc[0].y) + (acc[0].z + acc[0].w);
            v.y = (acc[1].x + acc[1].y) + (acc[1].z + acc[1].w);
            *(float2*)(&red_s[kc * RS1 + bp * RS2 + rg * 2]) = v;
        }
        if (pf && (wv == 4 || wv == 5)) {   // stage x_A(t+1)
            *(f32x4*)(&x_sw[stRow * XLD + sphys]) = xst;
        }
        __syncthreads();   // B2a: red_A ready; x_A staged

        if (wv == 0 && lane < 32) {   // epilogue A + publish
            float sg[4];
            #pragma unroll
            for (int g = 0; g < 4; ++g) {
                float s = bias_g[g];
                #pragma unroll
                for (int k2 = 0; k2 < 8; ++k2)
                    s += red_s[k2 * RS1 + eb * RS2 + g * 16 + ejj];
                sg[g] = s;
            }
            float cn = sigf(sg[1]) * c_reg + sigf(sg[0]) * tanhf(sg[2]);
            float hn = sigf(sg[3]) * tanhf(cn);
            c_reg = cn;
            p_s[lane] = hn * wz_r;
            __hip_atomic_store(
                hbuf + (parOut + bA0 + eb) * HH + j0 + ejj,
                packh((unsigned)(t + 1), hn),
                __ATOMIC_RELAXED, __HIP_MEMORY_SCOPE_AGENT);
        }

        // ================= B half =================
        acc[0] = make_float4(0.f, 0.f, 0.f, 0.f);
        acc[1] = make_float4(0.f, 0.f, 0.f, 0.f);
        {   // phase 1: x partials
            const float* xb = &x_sw[(2 + bp) * XLD + kc * 36];
            #pragma unroll
            for (int mi = 0; mi < 8; ++mi) {
                float4 xv4 = *(const float4*)(xb + mi * 4);
                #pragma unroll
                for (int i = 0; i < 2; ++i) {
                    float4 w = wih_r[i * 8 + mi];
                    acc[i].x += w.x * xv4.x; acc[i].y += w.y * xv4.y;
                    acc[i].z += w.z * xv4.z; acc[i].w += w.w * xv4.w;
                }
            }
        }
        if (t > 0 && inB) {   // spin-consume h_B(t-1)
            const unsigned want = (unsigned)t;
            unsigned long long* hp =
                hbuf + (parIn + bB0 + bcb) * HH + bcw;
            unsigned long long v0, v1;
            v0 = __hip_atomic_load(hp + 0, __ATOMIC_RELAXED, __HIP_MEMORY_SCOPE_AGENT);
            v1 = __hip_atomic_load(hp + 1, __ATOMIC_RELAXED, __HIP_MEMORY_SCOPE_AGENT);
            while ((unsigned)(v0 >> 32) != want)
                v0 = __hip_atomic_load(hp + 0, __ATOMIC_RELAXED, __HIP_MEMORY_SCOPE_AGENT);
            while ((unsigned)(v1 >> 32) != want)
                v1 = __hip_atomic_load(hp + 1, __ATOMIC_RELAXED, __HIP_MEMORY_SCOPE_AGENT);
            union { unsigned u; float f; } c0, c1;
            c0.u = (unsigned)v0; c1.u = (unsigned)v1;
            *(float2*)(&h_sw[(2 + bcb) * XLD + bcph]) = make_float2(c0.f, c1.f);
        }
        if (pf && (wv == 6 || wv == 7)) {   // B-stage issue after polls
            xst = ((const f32x4*)(emb + (long)tok_st * EE))[lane];
            if (t + 2 < TT) tok_st = sent[(t + 2) * NB + bB0 + stb];
        }
        __syncthreads();   // B1b: h_B ready; x_B(t) reads done

        if (t > 0 && wv == 3 && lane < 2) {   // part B(t-1)
            float s = 0.f;
            #pragma unroll
            for (int jj = 0; jj < 16; ++jj) s += p_s[32 + lane * 16 + jj];
            part[((size_t)(t - 1) * PJ + js) * NB + bB0 + lane] = s;
        }
        if (t > 0) {   // phase 2: h partials
            const float* hb = &h_sw[(2 + bp) * XLD + kc * 36];
            #pragma unroll
            for (int mi = 0; mi < 8; ++mi) {
                float4 hv4 = *(const float4*)(hb + mi * 4);
                #pragma unroll
                for (int i = 0; i < 2; ++i) {
                    float4 w = whh_r[i * 8 + mi];
                    acc[i].x += w.x * hv4.x; acc[i].y += w.y * hv4.y;
                    acc[i].z += w.z * hv4.z; acc[i].w += w.w * hv4.w;
                }
            }
        }
        {   // horizontal add -> red_s (B region)
            float2 v;
            v.x = (acc[0].x + acc[0].y) + (acc[0].z + acc[0].w);
            v.y = (acc[1].x + acc[1].y) + (acc[1].z + acc[1].w);
            *(float2*)(&red_s[RBOFF + kc * RS1 + bp * RS2 + rg * 2]) = v;
        }
        if (pf && (wv == 6 || wv == 7)) {   // stage x_B(t+1)
            *(f32x4*)(&x_sw[stRow * XLD + sphys]) = xst;
        }
        __syncthreads();   // B2b: red_B ready; x_B staged

        if (wv == 1 && lane < 32) {   // epilogue B + publish
            float sg[4];
            #pragma unroll
            for (int g = 0; g < 4; ++g) {
                float s = bias_g[g];
                #pragma unroll
                for (int k2 = 0; k2 < 8; ++k2)
                    s += red_s[RBOFF + k2 * RS1 + eb * RS2 + g * 16 + ejj];
                sg[g] = s;
            }
            float cn = sigf(sg[1]) * c_reg + sigf(sg[0]) * tanhf(sg[2]);
            float hn = sigf(sg[3]) * tanhf(cn);
            c_reg = cn;
            p_s[32 + lane] = hn * wz_r;
            __hip_atomic_store(
                hbuf + (parOut + bB0 + eb) * HH + j0 + ejj,
                packh((unsigned)(t + 1), hn),
                __ATOMIC_RELAXED, __HIP_MEMORY_SCOPE_AGENT);
        }
    }

    // final part-sums (t = TT-1)
    __syncthreads();
    if (wv == 2 && lane < 2) {
        float s = 0.f;
        #pragma unroll
        for (int jj = 0; jj < 16; ++jj) s += p_s[lane * 16 + jj];
        part[((size_t)(TT - 1) * PJ + js) * NB + bA0 + lane] = s;
    }
    if (wv == 3 && lane < 2) {
        float s = 0.f;
        #pragma unroll
        for (int jj = 0; jj < 16; ++jj) s += p_s[32 + lane * 16 + jj];
        part[((size_t)(TT - 1) * PJ + js) * NB + bB0 + lane] = s;
    }
}

__global__ void pz_kernel(const float* __restrict__ part,
                          const float* __restrict__ noise,
                          const float* __restrict__ b_z,
                          float* __restrict__ out)
{
    int idx = blockIdx.x * blockDim.x + threadIdx.x;  // t*64 + b
    if (idx >= TT * NB) return;
    int t = idx >> 6, b = idx & 63;
    float s = b_z[0];
    #pragma unroll
    for (int jg = 0; jg < PJ; ++jg) s += part[(t * PJ + jg) * NB + b];
    float pz = 1.f / (1.f + expf(-s));
    out[idx] = pz;
    out[TT * NB + idx] = (noise[idx] < pz) ? 1.f : 0.f;
}

// One block per batch column: stable compaction of tokens where z==1.
__global__ void compact_kernel(const int* __restrict__ sent,
                               const float* __restrict__ zbuf,
                               float* __restrict__ rat,
                               float* __restrict__ zsz)
{
    __shared__ float rat_s[TT];
    __shared__ int scan_s[256];
    int b = blockIdx.x, tid = threadIdx.x;
    int zloc[8];
    int base = tid * 8;
    int c = 0;
    #pragma unroll
    for (int i = 0; i < 8; ++i) {
        zloc[i] = (zbuf[(base + i) * NB + b] != 0.f) ? 1 : 0;
        c += zloc[i];
    }
    scan_s[tid] = c;
    for (int i = tid; i < TT; i += 256) rat_s[i] = 0.f;
    __syncthreads();
    for (int off = 1; off < 256; off <<= 1) {
        int v = scan_s[tid];
        int add = (tid >= off) ? scan_s[tid - off] : 0;
        __syncthreads();
        scan_s[tid] = v + add;
        __syncthreads();
    }
    int total = scan_s[255];
    int pos = scan_s[tid] - c;  // exclusive prefix
    #pragma unroll
    for (int i = 0; i < 8; ++i) {
        if (zloc[i]) { rat_s[pos] = (float)sent[(base + i) * NB + b]; ++pos; }
    }
    __syncthreads();
    for (int i = tid; i < TT; i += 256) rat[i * NB + b] = rat_s[i];
    if (tid == 0) zsz[b] = (float)total;
}

extern "C" void kernel_launch(void* const* d_in, const int* in_sizes, int n_in,
                              void* d_out, int out_size, void* d_ws, size_t ws_size,
                              hipStream_t stream)
{
    const int*   sent  = (const int*)d_in[0];
    const float* noise = (const float*)d_in[1];
    const float* emb   = (const float*)d_in[2];
    const float* W_ih  = (const float*)d_in[3];
    const float* W_hh  = (const float*)d_in[4];
    const float* b_ih  = (const float*)d_in[5];
    const float* b_hh  = (const float*)d_in[6];
    const float* W_z   = (const float*)d_in[7];
    const float* b_z   = (const float*)d_in[8];
    float* out = (float*)d_out;

    char* ws = (char*)d_ws;
    unsigned long long* hbuf = (unsigned long long*)ws;     // 2*64*256*8 = 256 KB
    float* part = (float*)(ws + 262144);                    // 2048*16*64*4 = 8 MB

    // tags must start != any expected tag (1..2048)
    (void)hipMemsetAsync(hbuf, 0, 2 * NB * HH * sizeof(unsigned long long), stream);

    // ~27KB static + 64KB dynamic -> ~91KB -> exactly 1 WG/CU
    lstm_kernel<<<256, 512, 65536, stream>>>(sent, emb, W_ih, W_hh, b_ih, b_hh,
                                             W_z, hbuf, part);
    pz_kernel<<<(TT * NB) / 256, 256, 0, stream>>>(part, noise, b_z, out);
    compact_kernel<<<NB, 256, 0, stream>>>(sent, out + TT * NB,
                                           out + 2 * TT * NB, out + 3 * TT * NB);
}